// Round 14
// baseline (94.289 us; speedup 1.0000x reference)
//
#include <hip/hip_runtime.h>
#include <hip/hip_bf16.h>
#include <cstdint>

#define KD 512
#define BM 256
#define NT 1024
#define NSPLIT 63
#define NNODES 127

typedef __attribute__((ext_vector_type(8))) short bf16x8;
typedef __attribute__((ext_vector_type(4))) float f32x4;

#define MFMA_B16(a, b, c) __builtin_amdgcn_mfma_f32_16x16x32_bf16(a, b, c, 0, 0, 0)
#define SCHED_FENCE() __builtin_amdgcn_sched_barrier(0)

static __device__ __forceinline__ unsigned short f2bf(float f) {
    return __builtin_bit_cast(unsigned short, __float2bfloat16(f));
}
static __device__ __forceinline__ float bf2f(unsigned short h) {
    return __builtin_bit_cast(float, (unsigned)h << 16);
}
static __device__ __forceinline__ unsigned pack2(float f0, float f1) {
    return (unsigned)f2bf(f0) | ((unsigned)f2bf(f1) << 16);
}

// 8 fp32 -> bf16 hi8 + residual lo8; named scalars only (stays in VGPRs)
static __device__ __forceinline__ void cvt8(f32x4 a, f32x4 b, bf16x8& hi, bf16x8& lo) {
    const unsigned short h0 = f2bf(a[0]), h1 = f2bf(a[1]), h2 = f2bf(a[2]), h3 = f2bf(a[3]);
    const unsigned short h4 = f2bf(b[0]), h5 = f2bf(b[1]), h6 = f2bf(b[2]), h7 = f2bf(b[3]);
    uint4 H = make_uint4((unsigned)h0 | ((unsigned)h1 << 16), (unsigned)h2 | ((unsigned)h3 << 16),
                         (unsigned)h4 | ((unsigned)h5 << 16), (unsigned)h6 | ((unsigned)h7 << 16));
    uint4 L = make_uint4(pack2(a[0] - bf2f(h0), a[1] - bf2f(h1)),
                         pack2(a[2] - bf2f(h2), a[3] - bf2f(h3)),
                         pack2(b[0] - bf2f(h4), b[1] - bf2f(h5)),
                         pack2(b[2] - bf2f(h6), b[3] - bf2f(h7)));
    hi = __builtin_bit_cast(bf16x8, H);
    lo = __builtin_bit_cast(bf16x8, L);
}

static __device__ __forceinline__ void gload_lds16(const void* g, void* l) {
    __builtin_amdgcn_global_load_lds(
        (const __attribute__((address_space(1))) unsigned int*)g,
        (__attribute__((address_space(3))) unsigned int*)l, 16, 0, 0);
}

// DFS path-min; lane p8 stores clipped nodes [p8*16, p8*16+16)
template<int T>
static __device__ __forceinline__ void tree_walk8(float qt, const float* __restrict__ srow,
                                                  float* __restrict__ zrow, int p8) {
    const float s  = srow[T];
    const float ql = fminf(qt, s);
    const float qr = fminf(qt, -s);
    if (((2 * T + 1) >> 4) == p8) zrow[2 * T + 1] = fminf(fmaxf(ql, 0.f), 1.f);
    if (((2 * T + 2) >> 4) == p8) zrow[2 * T + 2] = fminf(fmaxf(qr, 0.f), 1.f);
    if constexpr (2 * T + 1 < NSPLIT) tree_walk8<2 * T + 1>(ql, srow, zrow, p8);
    if constexpr (2 * T + 2 < NSPLIT) tree_walk8<2 * T + 2>(qr, srow, zrow, p8);
}

// ---------------- prep: A -> ws bf16 hi/lo planes [64][512], slot-swizzled:
// row r, k-group sk (8 k) stored at slot sk^(r&7): ushort idx = r*512 + (sk^(r&7))*8.
// hi plane at 0, lo plane at +32768 ushorts. 128 KB total; read linearly by DMA.
__global__ __launch_bounds__(256)
void lt_prep(const float* __restrict__ A, unsigned short* __restrict__ ws) {
    const int gid = blockIdx.x * 256 + threadIdx.x;   // 4096 total
    const int r   = gid >> 6;                         // 0..63
    const int sk  = gid & 63;
    const int k   = sk << 3;
    f32x4 a = (f32x4)(0.f), b = (f32x4)(0.f);
    if (r < NSPLIT) {
        a = *reinterpret_cast<const f32x4*>(A + (size_t)r * KD + k);
        b = *reinterpret_cast<const f32x4*>(A + (size_t)r * KD + k + 4);
    }
    bf16x8 hi, lo;
    cvt8(a, b, hi, lo);
    const int sl = sk ^ (r & 7);
    unsigned short* p = ws + r * 512 + sl * 8;
    *reinterpret_cast<bf16x8*>(p)         = hi;
    *reinterpret_cast<bf16x8*>(p + 32768) = lo;
}

// ---------------- one 32-k tile: ZERO barriers, ZERO asm waits.
// x: depth-4 rotating named slots (pure, monotone vm-queue -> compiler emits
// exact counted vmcnt(6)). B: read-only LDS, compiler pipelines freely.
template<int T>
static __device__ __forceinline__ void tiles(
        const float* xsl, const unsigned char* lds, int fr, int g,
        f32x4& v0a, f32x4& v0b, f32x4& v1a, f32x4& v1b,
        f32x4& v2a, f32x4& v2b, f32x4& v3a, f32x4& v3b, f32x4 (&acc)[4]) {
    constexpr int C = T & 3;
    f32x4 ca = (C == 0) ? v0a : (C == 1) ? v1a : (C == 2) ? v2a : v3a;
    f32x4 cb = (C == 0) ? v0b : (C == 1) ? v1b : (C == 2) ? v2b : v3b;
    bf16x8 ah, al;
    cvt8(ca, cb, ah, al);          // compiler-inserted vmcnt(6) lands here
    SCHED_FENCE();
    if constexpr (T + 4 < 16) {    // refill the slot just consumed
        f32x4& na = (C == 0) ? v0a : (C == 1) ? v1a : (C == 2) ? v2a : v3a;
        f32x4& nb = (C == 0) ? v0b : (C == 1) ? v1b : (C == 2) ? v2b : v3b;
        na = *reinterpret_cast<const f32x4*>(xsl + (T + 4) * 32);
        nb = *reinterpret_cast<const f32x4*>(xsl + (T + 4) * 32 + 4);
    }
    SCHED_FENCE();

    // B frags: row = nf*16+fr (stride 1024 B), slot (T*4+g)^(fr&7); hi/lo planes
    const int so = fr * 1024 + (((T << 2) + g) ^ (fr & 7)) * 16;
    bf16x8 b0 = *reinterpret_cast<const bf16x8*>(lds + so);
    bf16x8 b1 = *reinterpret_cast<const bf16x8*>(lds + 16384 + so);
    bf16x8 b2 = *reinterpret_cast<const bf16x8*>(lds + 32768 + so);
    bf16x8 b3 = *reinterpret_cast<const bf16x8*>(lds + 49152 + so);
    acc[0] = MFMA_B16(ah, b0, acc[0]);
    acc[1] = MFMA_B16(ah, b1, acc[1]);
    acc[2] = MFMA_B16(ah, b2, acc[2]);
    acc[3] = MFMA_B16(ah, b3, acc[3]);
    acc[0] = MFMA_B16(al, b0, acc[0]);
    acc[1] = MFMA_B16(al, b1, acc[1]);
    acc[2] = MFMA_B16(al, b2, acc[2]);
    acc[3] = MFMA_B16(al, b3, acc[3]);
    b0 = *reinterpret_cast<const bf16x8*>(lds + 65536 + so);        // lo plane
    b1 = *reinterpret_cast<const bf16x8*>(lds + 65536 + 16384 + so);
    b2 = *reinterpret_cast<const bf16x8*>(lds + 65536 + 32768 + so);
    b3 = *reinterpret_cast<const bf16x8*>(lds + 65536 + 49152 + so);
    acc[0] = MFMA_B16(ah, b0, acc[0]);
    acc[1] = MFMA_B16(ah, b1, acc[1]);
    acc[2] = MFMA_B16(ah, b2, acc[2]);
    acc[3] = MFMA_B16(ah, b3, acc[3]);

    if constexpr (T + 1 < 16)
        tiles<T + 1>(xsl, lds, fr, g,
                     v0a, v0b, v1a, v1b, v2a, v2b, v3a, v3b, acc);
}

// 16 waves x 16 rows = BM 256. LDS 128 KB (B hi+lo) -> 1 block/CU = 16 waves/CU.
__global__ __launch_bounds__(NT, 4)
void lt_mfma13(const float* __restrict__ x, const unsigned short* __restrict__ ws,
               float* __restrict__ out) {
    __shared__ __align__(16) unsigned char lds[131072];

    const int tid  = threadIdx.x;
    const int wave = tid >> 6;            // 0..15
    const int lane = tid & 63;
    const int fr   = lane & 15;
    const int g    = lane >> 4;
    const int r0   = blockIdx.x * BM;

    // x per-lane fragment source: row r0 + wave*16 + fr, k base g*8
    const float* xsl = x + (size_t)(r0 + wave * 16 + fr) * KD + g * 8;

    // prologue: copy B (128 KB, linear, swizzle baked in) via 8 DMA/wave
    {
        const unsigned char* bsrc = (const unsigned char*)ws + wave * 8192 + lane * 16;
        unsigned char* bdst = lds + wave * 8192;
#pragma unroll
        for (int i = 0; i < 8; ++i)
            gload_lds16(bsrc + i * 1024, bdst + i * 1024);
    }
    SCHED_FENCE();

    f32x4 acc[4];
#pragma unroll
    for (int j = 0; j < 4; ++j) acc[j] = (f32x4)(0.f);

    // x prefetch: tiles 0..3 into the 4 rotating slots
    f32x4 v0a = *reinterpret_cast<const f32x4*>(xsl);
    f32x4 v0b = *reinterpret_cast<const f32x4*>(xsl + 4);
    f32x4 v1a = *reinterpret_cast<const f32x4*>(xsl + 32);
    f32x4 v1b = *reinterpret_cast<const f32x4*>(xsl + 36);
    f32x4 v2a = *reinterpret_cast<const f32x4*>(xsl + 64);
    f32x4 v2b = *reinterpret_cast<const f32x4*>(xsl + 68);
    f32x4 v3a = *reinterpret_cast<const f32x4*>(xsl + 96);
    f32x4 v3b = *reinterpret_cast<const f32x4*>(xsl + 100);

    __syncthreads();   // one-time full drain: B resident; x slots already landed

    tiles<0>(xsl, lds, fr, g, v0a, v0b, v1a, v1b, v2a, v2b, v3a, v3b, acc);

    __syncthreads();   // everyone done reading B; region becomes epilogue scratch

    // ---- epilogue: wave-private 8 KB slice; 2 sub-phases of 8 rows
    float* warea = reinterpret_cast<float*>(lds + wave * 8192);   // [8][65]  = 2080 B
    float* zw    = warea + 520;                                   // [8][127] = 4064 B
    const int o  = lane >> 3;                                     // row 0..7
    const int p8 = lane & 7;                                      // nodes [p8*16,+16)

#pragma unroll
    for (int s = 0; s < 2; ++s) {
        if ((g >> 1) == s) {              // rows s*8..s*8+7 live in g = {2s, 2s+1}
#pragma unroll
            for (int nf = 0; nf < 4; ++nf)
#pragma unroll
                for (int rg = 0; rg < 4; ++rg)
                    warea[((g & 1) * 4 + rg) * 65 + nf * 16 + fr] = acc[nf][rg];
        }
        // same-wave LDS write->read ordering is in-order; no barrier needed
        const float* srow = warea + o * 65;
        float* zrow = zw + o * NNODES;
        if (p8 == 0) zrow[0] = 1.f;
        tree_walk8<0>(1.f, srow, zrow, p8);

        float* og = out + (size_t)(r0 + wave * 16 + s * 8) * NNODES;  // 16B-aligned
#pragma unroll
        for (int j = 0; j < 4; ++j) {
            const int idx = j * 64 + lane;
            if (idx < 254)
                *reinterpret_cast<f32x4*>(og + idx * 4) =
                    *reinterpret_cast<const f32x4*>(zw + idx * 4);
        }
    }
}

extern "C" void kernel_launch(void* const* d_in, const int* in_sizes, int n_in,
                              void* d_out, int out_size, void* d_ws, size_t ws_size,
                              hipStream_t stream) {
    const float* x = (const float*)d_in[0];          // [131072, 512]
    const float* A = (const float*)d_in[1];          // [63, 512]
    float* out = (float*)d_out;                      // [131072, 127]
    unsigned short* ws = (unsigned short*)d_ws;      // 128 KB B planes (prep'd)
    const int nrows = in_sizes[0] / KD;              // 131072
    lt_prep<<<dim3(16), dim3(256), 0, stream>>>(A, ws);
    lt_mfma13<<<dim3(nrows / BM), dim3(NT), 0, stream>>>(x, ws, out);
}

// Round 15
// 84.344 us; speedup vs baseline: 1.1179x; 1.1179x over previous
//
#include <hip/hip_runtime.h>
#include <hip/hip_bf16.h>
#include <cstdint>

#define KD 512
#define BM 128
#define NT 512
#define NSPLIT 63
#define NNODES 127
#define BH_OFF 65536       // B hi plane [64 rows][8 slots][16B] = 8 KB
#define BL_OFF 73728       // B lo plane; total LDS 80 KB -> 2 blocks/CU

typedef __attribute__((ext_vector_type(8))) short bf16x8;
typedef __attribute__((ext_vector_type(4))) float f32x4;

#define MFMA_B16(a, b, c) __builtin_amdgcn_mfma_f32_16x16x32_bf16(a, b, c, 0, 0, 0)
#define SCHED_FENCE() __builtin_amdgcn_sched_barrier(0)

static __device__ __forceinline__ unsigned short f2bf(float f) {
    return __builtin_bit_cast(unsigned short, __float2bfloat16(f));
}
static __device__ __forceinline__ float bf2f(unsigned short h) {
    return __builtin_bit_cast(float, (unsigned)h << 16);
}
static __device__ __forceinline__ unsigned pack2(float f0, float f1) {
    return (unsigned)f2bf(f0) | ((unsigned)f2bf(f1) << 16);
}

// 8 fp32 -> bf16 hi8 + residual lo8; named scalars only (stays in VGPRs)
static __device__ __forceinline__ void cvt8(f32x4 a, f32x4 b, bf16x8& hi, bf16x8& lo) {
    const unsigned short h0 = f2bf(a[0]), h1 = f2bf(a[1]), h2 = f2bf(a[2]), h3 = f2bf(a[3]);
    const unsigned short h4 = f2bf(b[0]), h5 = f2bf(b[1]), h6 = f2bf(b[2]), h7 = f2bf(b[3]);
    uint4 H = make_uint4((unsigned)h0 | ((unsigned)h1 << 16), (unsigned)h2 | ((unsigned)h3 << 16),
                         (unsigned)h4 | ((unsigned)h5 << 16), (unsigned)h6 | ((unsigned)h7 << 16));
    uint4 L = make_uint4(pack2(a[0] - bf2f(h0), a[1] - bf2f(h1)),
                         pack2(a[2] - bf2f(h2), a[3] - bf2f(h3)),
                         pack2(b[0] - bf2f(h4), b[1] - bf2f(h5)),
                         pack2(b[2] - bf2f(h6), b[3] - bf2f(h7)));
    hi = __builtin_bit_cast(bf16x8, H);
    lo = __builtin_bit_cast(bf16x8, L);
}

static __device__ __forceinline__ void gload_lds16(const void* g, void* l) {
    __builtin_amdgcn_global_load_lds(
        (const __attribute__((address_space(1))) unsigned int*)g,
        (__attribute__((address_space(3))) unsigned int*)l, 16, 0, 0);
}

template<int N> static __device__ __forceinline__ void vmwait() {
    if constexpr (N == 2) asm volatile("s_waitcnt vmcnt(2)" ::: "memory");
    else                  asm volatile("s_waitcnt vmcnt(0)" ::: "memory");
}

// DFS path-min; lane p8 stores clipped nodes [p8*16, p8*16+16)
template<int T>
static __device__ __forceinline__ void tree_walk8(float qt, const float* __restrict__ srow,
                                                  float* __restrict__ zrow, int p8) {
    const float s  = srow[T];
    const float ql = fminf(qt, s);
    const float qr = fminf(qt, -s);
    if (((2 * T + 1) >> 4) == p8) zrow[2 * T + 1] = fminf(fmaxf(ql, 0.f), 1.f);
    if (((2 * T + 2) >> 4) == p8) zrow[2 * T + 2] = fminf(fmaxf(qr, 0.f), 1.f);
    if constexpr (2 * T + 1 < NSPLIT) tree_walk8<2 * T + 1>(ql, srow, zrow, p8);
    if constexpr (2 * T + 2 < NSPLIT) tree_walk8<2 * T + 2>(qr, srow, zrow, p8);
}

// stage B k64 chunk from regs: [64 rows][8 slots][16B] per plane, slot = bq^(brow&7)
static __device__ __forceinline__ void write_B(unsigned char* lds, int brow, int sl,
                                               bool bvalid, f32x4 b0, f32x4 b1) {
    if (!bvalid) { b0 = (f32x4)(0.f); b1 = (f32x4)(0.f); }
    bf16x8 hi, lo;
    cvt8(b0, b1, hi, lo);
    *reinterpret_cast<bf16x8*>(lds + BH_OFF + brow * 128 + sl * 16) = hi;
    *reinterpret_cast<bf16x8*>(lds + BL_OFF + brow * 128 + sl * 16) = lo;
}

// stage x chunk c (k in [c*128, c*128+128)): 8 instrs, each 2 rows x 512B contiguous.
// LDS layout lands linearly as [16 rows][32 slots][16B]; slot holds k-piece s^(row&7).
static __device__ __forceinline__ void stage_x(const float* __restrict__ x, int rbase,
                                               int rl, int s, int c, unsigned char* xw) {
#pragma unroll
    for (int i = 0; i < 8; ++i) {
        const int row = 2 * i + rl;
        const float* src = x + (size_t)(rbase + row) * KD + c * 128
                             + ((s ^ (row & 7)) << 2);
        gload_lds16(src, xw + i * 1024);
    }
}

// one k=32 tile. x: wave-private single 8KB buffer per k128 chunk (512B DRAM runs).
// B: lt_mfma6 machinery at k64 cadence. Boundaries after odd T; stage at T%4==3.
template<int T>
static __device__ __forceinline__ void tiles(
        const float* __restrict__ x, int rbase, int rl, int s, unsigned char* xw,
        unsigned char* lds, const float* ag, bool bvalid, int brow, int sl,
        int fr, int g, f32x4 (&acc)[4], f32x4& bn0, f32x4& bn1) {
    // ---- x frags from own buffer (chunk T/4), swizzled 16B reads
    const int m  = fr & 7;
    const int uv = (T & 3) * 8 + g * 2;
    f32x4 va = *reinterpret_cast<const f32x4*>(xw + fr * 512 + ((uv ^ m) << 4));
    f32x4 vb = *reinterpret_cast<const f32x4*>(xw + fr * 512 + (((uv + 1) ^ m) << 4));
    bf16x8 ah, al;
    cvt8(va, vb, ah, al);

    // ---- B frags (hi), then hh + lh, then lo plane + hl
    const int bof = fr * 128 + ((((T & 1) * 4) + g) ^ m) * 16;
    const unsigned char* bh = lds + BH_OFF + bof;
    bf16x8 b0 = *reinterpret_cast<const bf16x8*>(bh);
    bf16x8 b1 = *reinterpret_cast<const bf16x8*>(bh + 2048);
    bf16x8 b2 = *reinterpret_cast<const bf16x8*>(bh + 4096);
    bf16x8 b3 = *reinterpret_cast<const bf16x8*>(bh + 6144);
    acc[0] = MFMA_B16(ah, b0, acc[0]);
    acc[1] = MFMA_B16(ah, b1, acc[1]);
    acc[2] = MFMA_B16(ah, b2, acc[2]);
    acc[3] = MFMA_B16(ah, b3, acc[3]);
    acc[0] = MFMA_B16(al, b0, acc[0]);
    acc[1] = MFMA_B16(al, b1, acc[1]);
    acc[2] = MFMA_B16(al, b2, acc[2]);
    acc[3] = MFMA_B16(al, b3, acc[3]);
    const unsigned char* bl = lds + BL_OFF + bof;
    b0 = *reinterpret_cast<const bf16x8*>(bl);
    b1 = *reinterpret_cast<const bf16x8*>(bl + 2048);
    b2 = *reinterpret_cast<const bf16x8*>(bl + 4096);
    b3 = *reinterpret_cast<const bf16x8*>(bl + 6144);
    acc[0] = MFMA_B16(ah, b0, acc[0]);
    acc[1] = MFMA_B16(ah, b1, acc[1]);
    acc[2] = MFMA_B16(ah, b2, acc[2]);
    acc[3] = MFMA_B16(ah, b3, acc[3]);

    // ---- boundary after odd T (except 15): B chunk b=(T+1)/2; x stage at T%4==3
    if constexpr ((T & 1) == 1 && T < 15) {
        SCHED_FENCE();
        if constexpr ((T & 3) == 3) {
            asm volatile("s_waitcnt lgkmcnt(0)" ::: "memory");  // own x reads done
            stage_x(x, rbase, rl, s, (T + 1) / 4, xw);           // overwrite own buf
        }
        SCHED_FENCE();
        __builtin_amdgcn_s_barrier();            // all waves done reading B chunk b-1
        write_B(lds, brow, sl, bvalid, bn0, bn1);   // compiler retires bn (vmcnt(8))
        asm volatile("s_waitcnt lgkmcnt(0)" ::: "memory");
        __builtin_amdgcn_s_barrier();            // B chunk b visible
        SCHED_FENCE();
        if constexpr ((T + 3) / 2 <= 7) {        // bn regs for chunk b+1 (L2-hot)
            if (bvalid) {
                bn0 = *reinterpret_cast<const f32x4*>(ag + ((T + 3) / 2) * 64);
                bn1 = *reinterpret_cast<const f32x4*>(ag + ((T + 3) / 2) * 64 + 4);
            }
        }
        SCHED_FENCE();
        if constexpr ((T & 3) == 3) {            // retire own stage; bn stays in flight
            vmwait<2>();
            SCHED_FENCE();
        }
    }
    if constexpr (T + 1 < 16)
        tiles<T + 1>(x, rbase, rl, s, xw, lds, ag, bvalid, brow, sl,
                     fr, g, acc, bn0, bn1);
}

// 8 waves x 16 rows; LDS 80 KB -> 2 blocks/CU = 16 waves/CU.
__global__ __launch_bounds__(NT, 4)
void lt_mfma14(const float* __restrict__ x, const float* __restrict__ A,
               float* __restrict__ out) {
    __shared__ __align__(16) unsigned char lds[81920];

    const int tid  = threadIdx.x;
    const int wave = tid >> 6;
    const int lane = tid & 63;
    const int fr   = lane & 15;
    const int g    = lane >> 4;
    const int r0   = blockIdx.x * BM;
    const int rbase = r0 + wave * 16;

    unsigned char* xw = lds + wave * 8192;   // wave-private x chunk buffer
    const int rl = lane >> 5;                // staging: row parity
    const int s  = lane & 31;                // staging: 16B slot in 512B run

    const int brow = tid >> 3;               // B staging: 8 thr/row, 8 k each
    const int bq   = tid & 7;
    const int sl   = bq ^ (brow & 7);
    const bool bvalid = brow < NSPLIT;
    const float* ag = A + (size_t)brow * KD + bq * 8;

    f32x4 acc[4];
#pragma unroll
    for (int j = 0; j < 4; ++j) acc[j] = (f32x4)(0.f);

    // prologue: bn0 regs FIRST (older than stage -> write_B waits bn only),
    // stage x chunk 0, write B chunk 0, barrier, bn1, retire stage (vmcnt(2)).
    f32x4 bn0 = (f32x4)(0.f), bn1 = (f32x4)(0.f);
    if (bvalid) {
        bn0 = *reinterpret_cast<const f32x4*>(ag);
        bn1 = *reinterpret_cast<const f32x4*>(ag + 4);
    }
    stage_x(x, rbase, rl, s, 0, xw);
    SCHED_FENCE();
    write_B(lds, brow, sl, bvalid, bn0, bn1);   // compiler vmcnt(8): x stage flies
    asm volatile("s_waitcnt lgkmcnt(0)" ::: "memory");
    __builtin_amdgcn_s_barrier();
    if (bvalid) {
        bn0 = *reinterpret_cast<const f32x4*>(ag + 64);
        bn1 = *reinterpret_cast<const f32x4*>(ag + 68);
    }
    SCHED_FENCE();
    vmwait<2>();                                // retire x chunk 0; bn1 in flight
    SCHED_FENCE();

    tiles<0>(x, rbase, rl, s, xw, lds, ag, bvalid, brow, sl, fr, g, acc, bn0, bn1);

    // ---- epilogue: fully wave-private (own 8 KB buffer), 2 sub-phases of 8 rows
    float* warea = reinterpret_cast<float*>(xw);      // [8][65]  = 2080 B
    float* zw    = warea + 520;                       // [8][127] = 4064 B, 16B-aligned
    const int o  = lane >> 3;                         // row 0..7
    const int p8 = lane & 7;                          // nodes [p8*16, +16)

#pragma unroll
    for (int sp = 0; sp < 2; ++sp) {
        if ((g >> 1) == sp) {                         // rows sp*8..+8 live in g={2sp,2sp+1}
#pragma unroll
            for (int nf = 0; nf < 4; ++nf)
#pragma unroll
                for (int rg = 0; rg < 4; ++rg)
                    warea[((g & 1) * 4 + rg) * 65 + nf * 16 + fr] = acc[nf][rg];
        }
        // same-wave LDS write->read ordering; no barriers after the K-loop
        const float* srow = warea + o * 65;
        float* zrow = zw + o * NNODES;
        if (p8 == 0) zrow[0] = 1.f;
        tree_walk8<0>(1.f, srow, zrow, p8);

        float* og = out + (size_t)(rbase + sp * 8) * NNODES;   // 16B-aligned
#pragma unroll
        for (int j = 0; j < 4; ++j) {
            const int idx = j * 64 + lane;
            if (idx < 254)
                *reinterpret_cast<f32x4*>(og + idx * 4) =
                    *reinterpret_cast<const f32x4*>(zw + idx * 4);
        }
    }
}

extern "C" void kernel_launch(void* const* d_in, const int* in_sizes, int n_in,
                              void* d_out, int out_size, void* d_ws, size_t ws_size,
                              hipStream_t stream) {
    const float* x = (const float*)d_in[0];   // [131072, 512]
    const float* A = (const float*)d_in[1];   // [63, 512]
    float* out = (float*)d_out;               // [131072, 127]
    const int nrows = in_sizes[0] / KD;       // 131072
    const int grid = nrows / BM;              // 1024 blocks
    lt_mfma14<<<dim3(grid), dim3(NT), 0, stream>>>(x, A, out);
}